// Round 19
// baseline (94.197 us; speedup 1.0000x reference)
//
#include <hip/hip_runtime.h>

typedef __attribute__((ext_vector_type(8))) __bf16 bf16x8;
typedef __attribute__((ext_vector_type(4))) __bf16 bf16x4;
typedef __attribute__((ext_vector_type(4))) float f32x4;
typedef __attribute__((ext_vector_type(8))) _Float16 f16x8;

#define LOG2E 1.44269504088896340736f

__device__ __forceinline__ void async_load16(const void* g, void* l) {
  __builtin_amdgcn_global_load_lds(
      (const __attribute__((address_space(1))) void*)g,
      (__attribute__((address_space(3))) void*)l, 16, 0, 0);
}

__device__ __forceinline__ float fast_exp2(float x) {
#if __has_builtin(__builtin_amdgcn_exp2f)
  return __builtin_amdgcn_exp2f(x);
#else
  return __expf(x * 0.6931471805599453f);
#endif
}

// ---------------- fp32 -> bf16 convert, 3 segments ----------------
__global__ void cvt3(const float* __restrict__ a, __bf16* __restrict__ oa, int na4,
                     const float* __restrict__ b, __bf16* __restrict__ ob, int nb4,
                     const float* __restrict__ c, __bf16* __restrict__ oc, int nc4) {
  int i = blockIdx.x * blockDim.x + threadIdx.x;
  int n = na4 + nb4 + nc4;
  int stride = gridDim.x * blockDim.x;
  for (; i < n; i += stride) {
    const float4* s;
    bf16x4* d;
    int j;
    if (i < na4) { s = (const float4*)a; d = (bf16x4*)oa; j = i; }
    else if (i < na4 + nb4) { s = (const float4*)b; d = (bf16x4*)ob; j = i - na4; }
    else { s = (const float4*)c; d = (bf16x4*)oc; j = i - na4 - nb4; }
    float4 v = s[j];
    bf16x4 o;
    o[0] = (__bf16)v.x; o[1] = (__bf16)v.y; o[2] = (__bf16)v.z; o[3] = (__bf16)v.w;
    d[j] = o;
  }
}

// ---------------- gemm1 (blocks 0..767) + ebias build (768..4863) ----------
// GEMM epilogue v2: C-tile staged through LDS (reusing the 32KB staging
// buffer) -> 8x 16B coalesced stores per thread instead of 64x 2B scalar
// stores (qk) / 16x strided 8B (vT). vT blocks stage TRANSPOSED [d][k].
__global__ __launch_bounds__(256) void gemm1_ebias(
    const __bf16* __restrict__ A,   // xb [8192][512]
    const __bf16* __restrict__ Bm,  // w1 [1536][512]
    const float* __restrict__ bias, // b_in [1536]
    __bf16* __restrict__ qkO,       // [8192][1024]
    __bf16* __restrict__ vT,        // [64][64][1024]
    const float* __restrict__ gbias, const float* __restrict__ bstr,
    _Float16* __restrict__ ebT) {
  __shared__ __align__(16) char smem[32768];
  const int t = threadIdx.x;

  if (blockIdx.x >= 768) {
    // ---- ebias table: ebT[(((b*64+qt)*32+kt)*64+lane)*8 + ni*4+r] ----
    const int gid = (blockIdx.x - 768) * 256 + t;
    const int lane = gid & 63;
    const int kt = (gid >> 6) & 31;
    const int qt = (gid >> 11) & 63;
    const int b = gid >> 17;
    const int g = lane >> 4, ln = lane & 15;
    const float alpha = 1.f / (1.f + __expf(-bstr[0]));
    const float bsc = 10.f * alpha * LOG2E;
    const float* base = gbias + (size_t)(b * 1024 + kt * 32 + ln) * 1024 + qt * 16 + g * 4;
    float4 va = *(const float4*)(base);              // ni=0 row
    float4 vb = *(const float4*)(base + 16 * 1024);  // ni=1 row
    float sv[8] = {va.x, va.y, va.z, va.w, vb.x, vb.y, vb.z, vb.w};
    f16x8 o;
#pragma unroll
    for (int i = 0; i < 8; ++i)
      o[i] = (_Float16)((1.f / (1.f + __expf(-sv[i])) - 0.5f) * bsc);
    *(f16x8*)(ebT + (size_t)gid * 8) = o;
    return;
  }

  // ---- GEMM part: M=8192, N=1536, K=512, 128x128 tile, XCD-chunked ----
  char* lA = smem;
  char* lB = smem + 16384;
  const int lane = t & 63;
  const int wid = t >> 6;
  const int wm = wid >> 1, wn = wid & 1;
  const int g = lane >> 4, ln = lane & 15;
  const int wg = (blockIdx.x & 7) * 96 + (blockIdx.x >> 3);  // 768/8 = 96
  const int m0 = (wg / 12) * 128;
  const int n0 = (wg % 12) * 128;

  const int srow = t >> 3;
  const int sswz = ((t & 7) * 16) ^ ((srow & 7) << 4);
  const size_t KB = 1024;  // K*2
  const char* gA = (const char*)A + (size_t)m0 * KB;
  const char* gB = (const char*)Bm + (size_t)n0 * KB;

  f32x4 acc[4][4] = {};

  for (int k0 = 0; k0 < 512; k0 += 64) {
    __syncthreads();
#pragma unroll
    for (int c = 0; c < 4; ++c) {
      int row = srow + 32 * c;
      async_load16(gA + (size_t)row * KB + k0 * 2 + sswz, lA + c * 4096 + t * 16);
      async_load16(gB + (size_t)row * KB + k0 * 2 + sswz, lB + c * 4096 + t * 16);
    }
    __syncthreads();
#pragma unroll
    for (int ks = 0; ks < 2; ++ks) {
      bf16x8 af[4], bf[4];
#pragma unroll
      for (int i = 0; i < 4; ++i) {
        int ar = wm * 64 + i * 16 + ln;
        int byo = (ks * 64 + g * 16) ^ ((ar & 7) << 4);
        af[i] = *(const bf16x8*)(lA + ar * 128 + byo);
        int br = wn * 64 + i * 16 + ln;
        bf[i] = *(const bf16x8*)(lB + br * 128 + byo);
      }
#pragma unroll
      for (int i = 0; i < 4; ++i)
#pragma unroll
        for (int j = 0; j < 4; ++j)
          acc[i][j] = __builtin_amdgcn_mfma_f32_16x16x32_bf16(af[i], bf[j], acc[i][j], 0, 0, 0);
    }
  }

  // ---- epilogue v2: LDS-staged coalesced C write ----
  __syncthreads();  // all waves done with staging-LDS frag reads
  const bool isV = (n0 >= 1024);
  // write phase: bf16 C-tile into LDS; [row][col] for qk, [col(d)][row(k)]
  // for vT (transpose free here). chunk-XOR ^(major&15) kills bank conflicts.
#pragma unroll
  for (int j = 0; j < 4; ++j) {
    int col = n0 + wn * 64 + j * 16 + ln;
    float bv = bias[col];
    float scale = (col < 512) ? (0.125f * LOG2E) : 1.0f;
    int coll = wn * 64 + j * 16 + ln;  // n-local 0..127
#pragma unroll
    for (int i = 0; i < 4; ++i) {
#pragma unroll
      for (int r = 0; r < 4; ++r) {
        int rowl = wm * 64 + i * 16 + g * 4 + r;  // m-local 0..127
        float v = (acc[i][j][r] + bv) * scale;
        int rr = isV ? coll : rowl;  // LDS major
        int cc = isV ? rowl : coll;  // LDS minor
        *(__bf16*)(smem + rr * 256 +
                   ((((cc >> 3) ^ (rr & 15)) << 4) | ((cc & 7) * 2))) = (__bf16)v;
      }
    }
  }
  __syncthreads();
  // read phase: thread t -> major line t>>1, half t&1; 8x 16B coalesced.
  {
    int rr = t >> 1;
    int hf = t & 1;
    char* dst;
    if (!isV) {
      dst = (char*)qkO + (size_t)(m0 + rr) * 2048 + (n0 + hf * 64) * 2;
    } else {
      int dglob = (n0 - 1024) + rr;  // 0..511
      int b = m0 >> 10;
      int h = dglob >> 6;
      int d = dglob & 63;
      dst = (char*)vT + (((size_t)(b * 8 + h) * 64 + d) * 1024 + (m0 & 1023)) * 2 + hf * 128;
    }
#pragma unroll
    for (int c = 0; c < 8; ++c) {
      int chunk = hf * 8 + c;
      bf16x8 v = *(const bf16x8*)(smem + rr * 256 + ((chunk ^ (rr & 15)) << 4));
      *(bf16x8*)(dst + c * 16) = v;
    }
  }
}

// ---------------- gemm2: out = attn @ w2^T + b_out (fp32) ----------------
__global__ __launch_bounds__(256) void gemm_bt0(
    const __bf16* __restrict__ A, const __bf16* __restrict__ Bm,
    const float* __restrict__ bias, float* __restrict__ C0,
    int M, int N, int K, int nt) {
  __shared__ __align__(16) char smem[32768];
  char* lA = smem;
  char* lB = smem + 16384;
  const int t = threadIdx.x;
  const int lane = t & 63;
  const int wid = t >> 6;
  const int wm = wid >> 1, wn = wid & 1;
  const int g = lane >> 4, ln = lane & 15;
  const int qchunk = gridDim.x >> 3;
  const int wg = (blockIdx.x & 7) * qchunk + (blockIdx.x >> 3);
  const int m0 = (wg / nt) * 128;
  const int n0 = (wg % nt) * 128;

  const int srow = t >> 3;
  const int sswz = ((t & 7) * 16) ^ ((srow & 7) << 4);
  const size_t KB = (size_t)K * 2;
  const char* gA = (const char*)A + (size_t)m0 * KB;
  const char* gB = (const char*)Bm + (size_t)n0 * KB;

  f32x4 acc[4][4] = {};

  for (int k0 = 0; k0 < K; k0 += 64) {
    __syncthreads();
#pragma unroll
    for (int c = 0; c < 4; ++c) {
      int row = srow + 32 * c;
      async_load16(gA + (size_t)row * KB + k0 * 2 + sswz, lA + c * 4096 + t * 16);
      async_load16(gB + (size_t)row * KB + k0 * 2 + sswz, lB + c * 4096 + t * 16);
    }
    __syncthreads();
#pragma unroll
    for (int ks = 0; ks < 2; ++ks) {
      bf16x8 af[4], bf[4];
#pragma unroll
      for (int i = 0; i < 4; ++i) {
        int ar = wm * 64 + i * 16 + ln;
        int byo = (ks * 64 + g * 16) ^ ((ar & 7) << 4);
        af[i] = *(const bf16x8*)(lA + ar * 128 + byo);
        int br = wn * 64 + i * 16 + ln;
        bf[i] = *(const bf16x8*)(lB + br * 128 + byo);
      }
#pragma unroll
      for (int i = 0; i < 4; ++i)
#pragma unroll
        for (int j = 0; j < 4; ++j)
          acc[i][j] = __builtin_amdgcn_mfma_f32_16x16x32_bf16(af[i], bf[j], acc[i][j], 0, 0, 0);
    }
  }

#pragma unroll
  for (int j = 0; j < 4; ++j) {
    int col = n0 + wn * 64 + j * 16 + ln;
    float bv = bias[col];
#pragma unroll
    for (int i = 0; i < 4; ++i) {
      int row0 = m0 + wm * 64 + i * 16 + g * 4;
#pragma unroll
      for (int r = 0; r < 4; ++r)
        C0[(size_t)(row0 + r) * N + col] = acc[i][j][r] + bv;
    }
  }
}

// ---------------- fused flash attention: cooperative K/V, 4 tiles/period --
// (R17-validated: 512 blocks = (b,h,qg), 8 waves, 8 periods, 72KB LDS)
__global__ __launch_bounds__(512, 4) void attn_fused(
    const __bf16* __restrict__ qk,    // [B][N][1024]: q(log2-prescaled)|k
    const __bf16* __restrict__ vT,    // [B*8][64 d][1024 k]
    const _Float16* __restrict__ ebT, // f16 bias table
    __bf16* __restrict__ attn) {      // [B][N][512]
  __shared__ __align__(16) char smem[73728];
  const int t = threadIdx.x;
  const int lane = t & 63;
  const int wid = t >> 6;               // 0..7 = q-tile within group
  const int g = lane >> 4, ln = lane & 15;
  const int wg = ((blockIdx.x & 7) << 6) + (blockIdx.x >> 3);  // XCD: b = wg>>6
  const int b = wg >> 6;
  const int rem = wg & 63;
  const int h = rem >> 3;               // head (shared by whole block)
  const int qg = rem & 7;
  const int qt = qg * 8 + wid;          // this wave's q-tile
  const int q0 = qt << 4;

  // buffer set s at smem + s*32768: [K0..K3 4K each][V0..V3 4K each]
  char* Ps = smem + 65536 + wid * 1024;  // per-wave P round-trip

  bf16x8 qf[2];
#pragma unroll
  for (int ks = 0; ks < 2; ++ks)
    qf[ks] = *(const bf16x8*)(qk + ((size_t)b * 1024 + q0 + ln) * 1024 +
                              h * 64 + ks * 32 + g * 8);

  float l_acc[4] = {0.f, 0.f, 0.f, 0.f};
  f32x4 o_acc[4] = {};

  const int krow = lane >> 3;
  const int ksrc = ((lane & 7) * 16) ^ (krow << 4);
  const int vrow = lane >> 2;
  const int vsrc = ((lane & 3) * 16) ^ ((vrow & 3) << 4);

  const char* qkb = (const char*)qk + (size_t)b * 1024 * 2048;
  const char* vTb = (const char*)vT + (size_t)(b * 8 + h) * 64 * 2048;
  const _Float16* ebp = ebT + (size_t)((b * 64 + qt) * 32) * 512 + lane * 8;

  auto stage = [&](int p, char* set) {
    if (wid < 4) {
#pragma unroll
      for (int j = 0; j < 4; ++j)
        async_load16(qkb + (size_t)((4 * p + j) * 32 + wid * 8 + krow) * 2048 +
                         1024 + h * 128 + ksrc,
                     set + j * 4096 + wid * 1024 + lane * 16);
    } else {
      int cc = wid - 4;
#pragma unroll
      for (int j = 0; j < 4; ++j)
        async_load16(vTb + (size_t)(cc * 16 + vrow) * 2048 + (size_t)(4 * p + j) * 64 + vsrc,
                     set + 16384 + j * 4096 + cc * 1024 + lane * 16);
    }
  };

  auto process = [&](const char* Kp, const char* Vp, f16x8 ebv) {
    bf16x8 kf[2][2];
#pragma unroll
    for (int ni = 0; ni < 2; ++ni) {
      int br = ni * 16 + ln;
      int sw = (br & 7) << 4;
#pragma unroll
      for (int ks = 0; ks < 2; ++ks)
        kf[ni][ks] = *(const bf16x8*)(Kp + br * 128 + ((ks * 64 + g * 16) ^ sw));
    }
    bf16x8 vf[4];
#pragma unroll
    for (int di = 0; di < 4; ++di)
      vf[di] = *(const bf16x8*)(Vp + (di * 16 + ln) * 64 + ((g * 16) ^ ((ln & 3) << 4)));

    f32x4 lbf0 = {(float)ebv[0], (float)ebv[1], (float)ebv[2], (float)ebv[3]};
    f32x4 lbf1 = {(float)ebv[4], (float)ebv[5], (float)ebv[6], (float)ebv[7]};
    f32x4 s[2];
    s[0] = __builtin_amdgcn_mfma_f32_16x16x32_bf16(qf[0], kf[0][0], lbf0, 0, 0, 0);
    s[0] = __builtin_amdgcn_mfma_f32_16x16x32_bf16(qf[1], kf[0][1], s[0], 0, 0, 0);
    s[1] = __builtin_amdgcn_mfma_f32_16x16x32_bf16(qf[0], kf[1][0], lbf1, 0, 0, 0);
    s[1] = __builtin_amdgcn_mfma_f32_16x16x32_bf16(qf[1], kf[1][1], s[1], 0, 0, 0);

#pragma unroll
    for (int r = 0; r < 4; ++r) {
      float p0 = fast_exp2(s[0][r]);
      float p1 = fast_exp2(s[1][r]);
      s[0][r] = p0; s[1][r] = p1;
      l_acc[r] += p0 + p1;
    }
#pragma unroll
    for (int ni = 0; ni < 2; ++ni)
#pragma unroll
      for (int r = 0; r < 4; ++r) {
        int q = g * 4 + r;
        *(__bf16*)(Ps + q * 64 + ((ni * 32 + ln * 2) ^ (((q >> 1) & 3) << 4))) =
            (__bf16)s[ni][r];
      }
    bf16x8 pf = *(const bf16x8*)(Ps + ln * 64 + ((g * 16) ^ (((ln >> 1) & 3) << 4)));

#pragma unroll
    for (int di = 0; di < 4; ++di)
      o_acc[di] = __builtin_amdgcn_mfma_f32_16x16x32_bf16(pf, vf[di], o_acc[di], 0, 0, 0);
  };

  stage(0, smem);
  f16x8 eb0 = *(const f16x8*)(ebp);
  f16x8 eb1 = *(const f16x8*)(ebp + 512);
  f16x8 eb2 = *(const f16x8*)(ebp + 1024);
  f16x8 eb3 = *(const f16x8*)(ebp + 1536);
  asm volatile("s_waitcnt vmcnt(0)" ::: "memory");
  __syncthreads();

  for (int p = 0; p < 8; ++p) {
    char* cur = smem + (p & 1) * 32768;
    char* nxt = smem + ((p + 1) & 1) * 32768;
    const int pn = (p + 1) & 7;

    stage(pn, nxt);
    f16x8 ebn0 = *(const f16x8*)(ebp + (size_t)(4 * pn) * 512);
    f16x8 ebn1 = *(const f16x8*)(ebp + (size_t)(4 * pn + 1) * 512);
    f16x8 ebn2 = *(const f16x8*)(ebp + (size_t)(4 * pn + 2) * 512);
    f16x8 ebn3 = *(const f16x8*)(ebp + (size_t)(4 * pn + 3) * 512);
    __builtin_amdgcn_sched_barrier(0);

    process(cur,         cur + 16384, eb0);
    process(cur + 4096,  cur + 20480, eb1);
    process(cur + 8192,  cur + 24576, eb2);
    process(cur + 12288, cur + 28672, eb3);

    asm volatile("s_waitcnt vmcnt(0)" ::: "memory");
    __builtin_amdgcn_sched_barrier(0);
    __syncthreads();
    eb0 = ebn0; eb1 = ebn1; eb2 = ebn2; eb3 = ebn3;
  }

#pragma unroll
  for (int r = 0; r < 4; ++r) {
    float rs = l_acc[r];
#pragma unroll
    for (int off = 1; off < 16; off <<= 1)
      rs += __shfl_xor(rs, off, 64);
    float inv = 1.f / rs;
    int q = q0 + g * 4 + r;
#pragma unroll
    for (int di = 0; di < 4; ++di)
      attn[((size_t)b * 1024 + q) * 512 + h * 64 + di * 16 + ln] =
          (__bf16)(o_acc[di][r] * inv);
  }
}

extern "C" void kernel_launch(void* const* d_in, const int* in_sizes, int n_in,
                              void* d_out, int out_size, void* d_ws, size_t ws_size,
                              hipStream_t stream) {
  const float* x     = (const float*)d_in[0];
  const float* gb    = (const float*)d_in[1];
  const float* w_in  = (const float*)d_in[2];
  const float* b_in  = (const float*)d_in[3];
  const float* w_out = (const float*)d_in[4];
  const float* b_out = (const float*)d_in[5];
  const float* bstr  = (const float*)d_in[6];

  char* ws = (char*)d_ws;
  __bf16* qk    = (__bf16*)(ws);                      // 16,777,216 B
  __bf16* vT    = (__bf16*)(ws + 16777216);           //  8,388,608 B
  __bf16* xb    = (__bf16*)(ws + 25165824);           //  8,388,608 B
  __bf16* w1    = (__bf16*)(ws + 33554432);           //  1,572,864 B
  __bf16* w2    = (__bf16*)(ws + 35127296);           //    524,288 B
  _Float16* ebT = (_Float16*)(ws + 35651584);         // 16,777,216 B
  __bf16* attn_buf = xb;  // alias: x_bf16 dead after GEMM1

  cvt3<<<2560, 256, 0, stream>>>(x, xb, (8 * 1024 * 512) / 4,
                                 w_in, w1, (1536 * 512) / 4,
                                 w_out, w2, (512 * 512) / 4);

  gemm1_ebias<<<768 + 4096, 256, 0, stream>>>(xb, w1, b_in, qk, vT, gb, bstr, ebT);
  attn_fused<<<512, 512, 0, stream>>>(qk, vT, ebT, attn_buf);
  gemm_bt0<<<256, 256, 0, stream>>>(attn_buf, w2, b_out, (float*)d_out, 8192, 512, 512, 4);
}

// Round 20
// 84.623 us; speedup vs baseline: 1.1131x; 1.1131x over previous
//
#include <hip/hip_runtime.h>

typedef __attribute__((ext_vector_type(8))) __bf16 bf16x8;
typedef __attribute__((ext_vector_type(4))) __bf16 bf16x4;
typedef __attribute__((ext_vector_type(4))) float f32x4;
typedef __attribute__((ext_vector_type(8))) _Float16 f16x8;

#define LOG2E 1.44269504088896340736f

__device__ __forceinline__ void async_load16(const void* g, void* l) {
  __builtin_amdgcn_global_load_lds(
      (const __attribute__((address_space(1))) void*)g,
      (__attribute__((address_space(3))) void*)l, 16, 0, 0);
}

__device__ __forceinline__ float fast_exp2(float x) {
#if __has_builtin(__builtin_amdgcn_exp2f)
  return __builtin_amdgcn_exp2f(x);
#else
  return __expf(x * 0.6931471805599453f);
#endif
}

// ---------------- fp32 -> bf16 convert, 3 segments ----------------
__global__ void cvt3(const float* __restrict__ a, __bf16* __restrict__ oa, int na4,
                     const float* __restrict__ b, __bf16* __restrict__ ob, int nb4,
                     const float* __restrict__ c, __bf16* __restrict__ oc, int nc4) {
  int i = blockIdx.x * blockDim.x + threadIdx.x;
  int n = na4 + nb4 + nc4;
  int stride = gridDim.x * blockDim.x;
  for (; i < n; i += stride) {
    const float4* s;
    bf16x4* d;
    int j;
    if (i < na4) { s = (const float4*)a; d = (bf16x4*)oa; j = i; }
    else if (i < na4 + nb4) { s = (const float4*)b; d = (bf16x4*)ob; j = i - na4; }
    else { s = (const float4*)c; d = (bf16x4*)oc; j = i - na4 - nb4; }
    float4 v = s[j];
    bf16x4 o;
    o[0] = (__bf16)v.x; o[1] = (__bf16)v.y; o[2] = (__bf16)v.z; o[3] = (__bf16)v.w;
    d[j] = o;
  }
}

// ---------------- gemm1 (blocks 0..767) + ebias build (768..2815) ----------
// 512 threads: 8 waves per 128x128 tile (wave tile 64x32, acc[4][2]) --
// doubles waves/CU vs the 4-wave version. Epilogue = R18 direct stores.
__global__ __launch_bounds__(512, 4) void gemm1_ebias(
    const __bf16* __restrict__ A,   // xb [8192][512]
    const __bf16* __restrict__ Bm,  // w1 [1536][512]
    const float* __restrict__ bias, // b_in [1536]
    __bf16* __restrict__ qkO,       // [8192][1024]
    __bf16* __restrict__ vT,        // [64][64][1024]
    const float* __restrict__ gbias, const float* __restrict__ bstr,
    _Float16* __restrict__ ebT) {
  __shared__ __align__(16) char smem[32768];
  const int t = threadIdx.x;

  if (blockIdx.x >= 768) {
    // ---- ebias table: ebT[(((b*64+qt)*32+kt)*64+lane)*8 + ni*4+r] ----
    const int gid = (blockIdx.x - 768) * 512 + t;  // 2048 blocks x 512 = 1M
    const int lane = gid & 63;
    const int kt = (gid >> 6) & 31;
    const int qt = (gid >> 11) & 63;
    const int b = gid >> 17;
    const int g = lane >> 4, ln = lane & 15;
    const float alpha = 1.f / (1.f + __expf(-bstr[0]));
    const float bsc = 10.f * alpha * LOG2E;
    const float* base = gbias + (size_t)(b * 1024 + kt * 32 + ln) * 1024 + qt * 16 + g * 4;
    float4 va = *(const float4*)(base);              // ni=0 row
    float4 vb = *(const float4*)(base + 16 * 1024);  // ni=1 row
    float sv[8] = {va.x, va.y, va.z, va.w, vb.x, vb.y, vb.z, vb.w};
    f16x8 o;
#pragma unroll
    for (int i = 0; i < 8; ++i)
      o[i] = (_Float16)((1.f / (1.f + __expf(-sv[i])) - 0.5f) * bsc);
    *(f16x8*)(ebT + (size_t)gid * 8) = o;
    return;
  }

  // ---- GEMM: M=8192, N=1536, K=512, 128x128 tile, 8 waves (64x32 each) ----
  char* lA = smem;
  char* lB = smem + 16384;
  const int lane = t & 63;
  const int wid = t >> 6;              // 0..7
  const int wm = wid >> 2, wn = wid & 3;
  const int g = lane >> 4, ln = lane & 15;
  const int wg = (blockIdx.x & 7) * 96 + (blockIdx.x >> 3);  // 768/8 = 96
  const int m0 = (wg / 12) * 128;
  const int n0 = (wg % 12) * 128;

  const int srow = t >> 3;             // 0..63
  const int sswz = ((t & 7) * 16) ^ ((srow & 7) << 4);
  const size_t KB = 1024;  // K*2
  const char* gA = (const char*)A + (size_t)m0 * KB;
  const char* gB = (const char*)Bm + (size_t)n0 * KB;

  f32x4 acc[4][2] = {};

  for (int k0 = 0; k0 < 512; k0 += 64) {
    __syncthreads();
#pragma unroll
    for (int c = 0; c < 2; ++c) {
      int row = srow + 64 * c;  // (row&7)==(srow&7)
      async_load16(gA + (size_t)row * KB + k0 * 2 + sswz, lA + c * 8192 + t * 16);
      async_load16(gB + (size_t)row * KB + k0 * 2 + sswz, lB + c * 8192 + t * 16);
    }
    __syncthreads();
#pragma unroll
    for (int ks = 0; ks < 2; ++ks) {
      bf16x8 af[4], bf[2];
#pragma unroll
      for (int i = 0; i < 4; ++i) {
        int ar = wm * 64 + i * 16 + ln;
        af[i] = *(const bf16x8*)(lA + ar * 128 + ((ks * 64 + g * 16) ^ ((ar & 7) << 4)));
      }
#pragma unroll
      for (int j = 0; j < 2; ++j) {
        int br = wn * 32 + j * 16 + ln;
        bf[j] = *(const bf16x8*)(lB + br * 128 + ((ks * 64 + g * 16) ^ ((br & 7) << 4)));
      }
#pragma unroll
      for (int i = 0; i < 4; ++i)
#pragma unroll
        for (int j = 0; j < 2; ++j)
          acc[i][j] = __builtin_amdgcn_mfma_f32_16x16x32_bf16(af[i], bf[j], acc[i][j], 0, 0, 0);
    }
  }

  // epilogue: R18-style direct stores
#pragma unroll
  for (int j = 0; j < 2; ++j) {
    int col = n0 + wn * 32 + j * 16 + ln;
    float bv = bias[col];
    if (col < 1024) {
      float scale = (col < 512) ? (0.125f * LOG2E) : 1.0f;
#pragma unroll
      for (int i = 0; i < 4; ++i) {
        int row0 = m0 + wm * 64 + i * 16 + g * 4;
#pragma unroll
        for (int r = 0; r < 4; ++r)
          qkO[(size_t)(row0 + r) * 1024 + col] = (__bf16)((acc[i][j][r] + bv) * scale);
      }
    } else {
      int h = (col - 1024) >> 6;
      int d = (col - 1024) & 63;
#pragma unroll
      for (int i = 0; i < 4; ++i) {
        int row0 = m0 + wm * 64 + i * 16 + g * 4;
        int b = row0 >> 10;
        bf16x4 pk;
#pragma unroll
        for (int r = 0; r < 4; ++r) pk[r] = (__bf16)(acc[i][j][r] + bv);
        *(bf16x4*)(vT + (((size_t)b * 8 + h) * 64 + d) * 1024 + (row0 & 1023)) = pk;
      }
    }
  }
}

// ---------------- gemm2: out = attn @ w2^T + b_out (fp32), 8 waves --------
__global__ __launch_bounds__(512, 4) void gemm_bt0(
    const __bf16* __restrict__ A, const __bf16* __restrict__ Bm,
    const float* __restrict__ bias, float* __restrict__ C0,
    int M, int N, int K, int nt) {
  __shared__ __align__(16) char smem[32768];
  char* lA = smem;
  char* lB = smem + 16384;
  const int t = threadIdx.x;
  const int lane = t & 63;
  const int wid = t >> 6;
  const int wm = wid >> 2, wn = wid & 3;
  const int g = lane >> 4, ln = lane & 15;
  const int qchunk = gridDim.x >> 3;
  const int wg = (blockIdx.x & 7) * qchunk + (blockIdx.x >> 3);
  const int m0 = (wg / nt) * 128;
  const int n0 = (wg % nt) * 128;

  const int srow = t >> 3;
  const int sswz = ((t & 7) * 16) ^ ((srow & 7) << 4);
  const size_t KB = (size_t)K * 2;
  const char* gA = (const char*)A + (size_t)m0 * KB;
  const char* gB = (const char*)Bm + (size_t)n0 * KB;

  f32x4 acc[4][2] = {};

  for (int k0 = 0; k0 < K; k0 += 64) {
    __syncthreads();
#pragma unroll
    for (int c = 0; c < 2; ++c) {
      int row = srow + 64 * c;
      async_load16(gA + (size_t)row * KB + k0 * 2 + sswz, lA + c * 8192 + t * 16);
      async_load16(gB + (size_t)row * KB + k0 * 2 + sswz, lB + c * 8192 + t * 16);
    }
    __syncthreads();
#pragma unroll
    for (int ks = 0; ks < 2; ++ks) {
      bf16x8 af[4], bf[2];
#pragma unroll
      for (int i = 0; i < 4; ++i) {
        int ar = wm * 64 + i * 16 + ln;
        af[i] = *(const bf16x8*)(lA + ar * 128 + ((ks * 64 + g * 16) ^ ((ar & 7) << 4)));
      }
#pragma unroll
      for (int j = 0; j < 2; ++j) {
        int br = wn * 32 + j * 16 + ln;
        bf[j] = *(const bf16x8*)(lB + br * 128 + ((ks * 64 + g * 16) ^ ((br & 7) << 4)));
      }
#pragma unroll
      for (int i = 0; i < 4; ++i)
#pragma unroll
        for (int j = 0; j < 2; ++j)
          acc[i][j] = __builtin_amdgcn_mfma_f32_16x16x32_bf16(af[i], bf[j], acc[i][j], 0, 0, 0);
    }
  }

#pragma unroll
  for (int j = 0; j < 2; ++j) {
    int col = n0 + wn * 32 + j * 16 + ln;
    float bv = bias[col];
#pragma unroll
    for (int i = 0; i < 4; ++i) {
      int row0 = m0 + wm * 64 + i * 16 + g * 4;
#pragma unroll
      for (int r = 0; r < 4; ++r)
        C0[(size_t)(row0 + r) * N + col] = acc[i][j][r] + bv;
    }
  }
}

// ---------------- fused flash attention: cooperative K/V, 4 tiles/period --
// (R17/R18-validated, byte-identical)
__global__ __launch_bounds__(512, 4) void attn_fused(
    const __bf16* __restrict__ qk,    // [B][N][1024]: q(log2-prescaled)|k
    const __bf16* __restrict__ vT,    // [B*8][64 d][1024 k]
    const _Float16* __restrict__ ebT, // f16 bias table
    __bf16* __restrict__ attn) {      // [B][N][512]
  __shared__ __align__(16) char smem[73728];
  const int t = threadIdx.x;
  const int lane = t & 63;
  const int wid = t >> 6;               // 0..7 = q-tile within group
  const int g = lane >> 4, ln = lane & 15;
  const int wg = ((blockIdx.x & 7) << 6) + (blockIdx.x >> 3);  // XCD: b = wg>>6
  const int b = wg >> 6;
  const int rem = wg & 63;
  const int h = rem >> 3;               // head (shared by whole block)
  const int qg = rem & 7;
  const int qt = qg * 8 + wid;          // this wave's q-tile
  const int q0 = qt << 4;

  // buffer set s at smem + s*32768: [K0..K3 4K each][V0..V3 4K each]
  char* Ps = smem + 65536 + wid * 1024;  // per-wave P round-trip

  bf16x8 qf[2];
#pragma unroll
  for (int ks = 0; ks < 2; ++ks)
    qf[ks] = *(const bf16x8*)(qk + ((size_t)b * 1024 + q0 + ln) * 1024 +
                              h * 64 + ks * 32 + g * 8);

  float l_acc[4] = {0.f, 0.f, 0.f, 0.f};
  f32x4 o_acc[4] = {};

  const int krow = lane >> 3;
  const int ksrc = ((lane & 7) * 16) ^ (krow << 4);
  const int vrow = lane >> 2;
  const int vsrc = ((lane & 3) * 16) ^ ((vrow & 3) << 4);

  const char* qkb = (const char*)qk + (size_t)b * 1024 * 2048;
  const char* vTb = (const char*)vT + (size_t)(b * 8 + h) * 64 * 2048;
  const _Float16* ebp = ebT + (size_t)((b * 64 + qt) * 32) * 512 + lane * 8;

  auto stage = [&](int p, char* set) {
    if (wid < 4) {
#pragma unroll
      for (int j = 0; j < 4; ++j)
        async_load16(qkb + (size_t)((4 * p + j) * 32 + wid * 8 + krow) * 2048 +
                         1024 + h * 128 + ksrc,
                     set + j * 4096 + wid * 1024 + lane * 16);
    } else {
      int cc = wid - 4;
#pragma unroll
      for (int j = 0; j < 4; ++j)
        async_load16(vTb + (size_t)(cc * 16 + vrow) * 2048 + (size_t)(4 * p + j) * 64 + vsrc,
                     set + 16384 + j * 4096 + cc * 1024 + lane * 16);
    }
  };

  auto process = [&](const char* Kp, const char* Vp, f16x8 ebv) {
    bf16x8 kf[2][2];
#pragma unroll
    for (int ni = 0; ni < 2; ++ni) {
      int br = ni * 16 + ln;
      int sw = (br & 7) << 4;
#pragma unroll
      for (int ks = 0; ks < 2; ++ks)
        kf[ni][ks] = *(const bf16x8*)(Kp + br * 128 + ((ks * 64 + g * 16) ^ sw));
    }
    bf16x8 vf[4];
#pragma unroll
    for (int di = 0; di < 4; ++di)
      vf[di] = *(const bf16x8*)(Vp + (di * 16 + ln) * 64 + ((g * 16) ^ ((ln & 3) << 4)));

    f32x4 lbf0 = {(float)ebv[0], (float)ebv[1], (float)ebv[2], (float)ebv[3]};
    f32x4 lbf1 = {(float)ebv[4], (float)ebv[5], (float)ebv[6], (float)ebv[7]};
    f32x4 s[2];
    s[0] = __builtin_amdgcn_mfma_f32_16x16x32_bf16(qf[0], kf[0][0], lbf0, 0, 0, 0);
    s[0] = __builtin_amdgcn_mfma_f32_16x16x32_bf16(qf[1], kf[0][1], s[0], 0, 0, 0);
    s[1] = __builtin_amdgcn_mfma_f32_16x16x32_bf16(qf[0], kf[1][0], lbf1, 0, 0, 0);
    s[1] = __builtin_amdgcn_mfma_f32_16x16x32_bf16(qf[1], kf[1][1], s[1], 0, 0, 0);

#pragma unroll
    for (int r = 0; r < 4; ++r) {
      float p0 = fast_exp2(s[0][r]);
      float p1 = fast_exp2(s[1][r]);
      s[0][r] = p0; s[1][r] = p1;
      l_acc[r] += p0 + p1;
    }
#pragma unroll
    for (int ni = 0; ni < 2; ++ni)
#pragma unroll
      for (int r = 0; r < 4; ++r) {
        int q = g * 4 + r;
        *(__bf16*)(Ps + q * 64 + ((ni * 32 + ln * 2) ^ (((q >> 1) & 3) << 4))) =
            (__bf16)s[ni][r];
      }
    bf16x8 pf = *(const bf16x8*)(Ps + ln * 64 + ((g * 16) ^ (((ln >> 1) & 3) << 4)));

#pragma unroll
    for (int di = 0; di < 4; ++di)
      o_acc[di] = __builtin_amdgcn_mfma_f32_16x16x32_bf16(pf, vf[di], o_acc[di], 0, 0, 0);
  };

  stage(0, smem);
  f16x8 eb0 = *(const f16x8*)(ebp);
  f16x8 eb1 = *(const f16x8*)(ebp + 512);
  f16x8 eb2 = *(const f16x8*)(ebp + 1024);
  f16x8 eb3 = *(const f16x8*)(ebp + 1536);
  asm volatile("s_waitcnt vmcnt(0)" ::: "memory");
  __syncthreads();

  for (int p = 0; p < 8; ++p) {
    char* cur = smem + (p & 1) * 32768;
    char* nxt = smem + ((p + 1) & 1) * 32768;
    const int pn = (p + 1) & 7;

    stage(pn, nxt);
    f16x8 ebn0 = *(const f16x8*)(ebp + (size_t)(4 * pn) * 512);
    f16x8 ebn1 = *(const f16x8*)(ebp + (size_t)(4 * pn + 1) * 512);
    f16x8 ebn2 = *(const f16x8*)(ebp + (size_t)(4 * pn + 2) * 512);
    f16x8 ebn3 = *(const f16x8*)(ebp + (size_t)(4 * pn + 3) * 512);
    __builtin_amdgcn_sched_barrier(0);

    process(cur,         cur + 16384, eb0);
    process(cur + 4096,  cur + 20480, eb1);
    process(cur + 8192,  cur + 24576, eb2);
    process(cur + 12288, cur + 28672, eb3);

    asm volatile("s_waitcnt vmcnt(0)" ::: "memory");
    __builtin_amdgcn_sched_barrier(0);
    __syncthreads();
    eb0 = ebn0; eb1 = ebn1; eb2 = ebn2; eb3 = ebn3;
  }

#pragma unroll
  for (int r = 0; r < 4; ++r) {
    float rs = l_acc[r];
#pragma unroll
    for (int off = 1; off < 16; off <<= 1)
      rs += __shfl_xor(rs, off, 64);
    float inv = 1.f / rs;
    int q = q0 + g * 4 + r;
#pragma unroll
    for (int di = 0; di < 4; ++di)
      attn[((size_t)b * 1024 + q) * 512 + h * 64 + di * 16 + ln] =
          (__bf16)(o_acc[di][r] * inv);
  }
}

extern "C" void kernel_launch(void* const* d_in, const int* in_sizes, int n_in,
                              void* d_out, int out_size, void* d_ws, size_t ws_size,
                              hipStream_t stream) {
  const float* x     = (const float*)d_in[0];
  const float* gb    = (const float*)d_in[1];
  const float* w_in  = (const float*)d_in[2];
  const float* b_in  = (const float*)d_in[3];
  const float* w_out = (const float*)d_in[4];
  const float* b_out = (const float*)d_in[5];
  const float* bstr  = (const float*)d_in[6];

  char* ws = (char*)d_ws;
  __bf16* qk    = (__bf16*)(ws);                      // 16,777,216 B
  __bf16* vT    = (__bf16*)(ws + 16777216);           //  8,388,608 B
  __bf16* xb    = (__bf16*)(ws + 25165824);           //  8,388,608 B
  __bf16* w1    = (__bf16*)(ws + 33554432);           //  1,572,864 B
  __bf16* w2    = (__bf16*)(ws + 35127296);           //    524,288 B
  _Float16* ebT = (_Float16*)(ws + 35651584);         // 16,777,216 B
  __bf16* attn_buf = xb;  // alias: x_bf16 dead after GEMM1

  cvt3<<<2560, 256, 0, stream>>>(x, xb, (8 * 1024 * 512) / 4,
                                 w_in, w1, (1536 * 512) / 4,
                                 w_out, w2, (512 * 512) / 4);

  // gemm1 (768 blocks, dispatched first) + ebias table (2048 blocks) fused
  gemm1_ebias<<<768 + 2048, 512, 0, stream>>>(xb, w1, b_in, qk, vT, gb, bstr, ebT);
  attn_fused<<<512, 512, 0, stream>>>(qk, vT, ebT, attn_buf);
  gemm_bt0<<<256, 512, 0, stream>>>(attn_buf, w2, b_out, (float*)d_out, 8192, 512, 512, 4);
}

// Round 21
// 81.795 us; speedup vs baseline: 1.1516x; 1.0346x over previous
//
#include <hip/hip_runtime.h>

typedef __attribute__((ext_vector_type(8))) __bf16 bf16x8;
typedef __attribute__((ext_vector_type(4))) __bf16 bf16x4;
typedef __attribute__((ext_vector_type(4))) float f32x4;
typedef __attribute__((ext_vector_type(8))) _Float16 f16x8;

#define LOG2E 1.44269504088896340736f

__device__ __forceinline__ void async_load16(const void* g, void* l) {
  __builtin_amdgcn_global_load_lds(
      (const __attribute__((address_space(1))) void*)g,
      (__attribute__((address_space(3))) void*)l, 16, 0, 0);
}

__device__ __forceinline__ float fast_exp2(float x) {
#if __has_builtin(__builtin_amdgcn_exp2f)
  return __builtin_amdgcn_exp2f(x);
#else
  return __expf(x * 0.6931471805599453f);
#endif
}

// ---------------- fp32 -> bf16 convert: w1 + w2 only (x folded into gemm1) -
__global__ void cvtW(const float* __restrict__ b, __bf16* __restrict__ ob, int nb4,
                     const float* __restrict__ c, __bf16* __restrict__ oc, int nc4) {
  int i = blockIdx.x * blockDim.x + threadIdx.x;
  int n = nb4 + nc4;
  int stride = gridDim.x * blockDim.x;
  for (; i < n; i += stride) {
    const float4* s;
    bf16x4* d;
    int j;
    if (i < nb4) { s = (const float4*)b; d = (bf16x4*)ob; j = i; }
    else { s = (const float4*)c; d = (bf16x4*)oc; j = i - nb4; }
    float4 v = s[j];
    bf16x4 o;
    o[0] = (__bf16)v.x; o[1] = (__bf16)v.y; o[2] = (__bf16)v.z; o[3] = (__bf16)v.w;
    d[j] = o;
  }
}

// ---------------- gemm1 (blocks 0..767) + ebias build (768..2815) ----------
// 512 threads, 8 waves (64x32 wave tile). A staged DIRECTLY from f32 x:
// reg-load 2x float4 (same XOR-swizzled element offsets as the bf16 gl_lds
// path -> byte-identical LDS image), convert, ds_write_b128. Kills the
// separate 25MB x-conversion pass. B stays global_load_lds from bf16 w1.
__global__ __launch_bounds__(512, 4) void gemm1_ebias(
    const float* __restrict__ X,    // x [8192][512] f32
    const __bf16* __restrict__ Bm,  // w1 [1536][512]
    const float* __restrict__ bias, // b_in [1536]
    __bf16* __restrict__ qkO,       // [8192][1024]
    __bf16* __restrict__ vT,        // [64][64][1024]
    const float* __restrict__ gbias, const float* __restrict__ bstr,
    _Float16* __restrict__ ebT) {
  __shared__ __align__(16) char smem[32768];
  const int t = threadIdx.x;

  if (blockIdx.x >= 768) {
    // ---- ebias table: ebT[(((b*64+qt)*32+kt)*64+lane)*8 + ni*4+r] ----
    const int gid = (blockIdx.x - 768) * 512 + t;  // 2048 x 512 = 1M
    const int lane = gid & 63;
    const int kt = (gid >> 6) & 31;
    const int qt = (gid >> 11) & 63;
    const int b = gid >> 17;
    const int g = lane >> 4, ln = lane & 15;
    const float alpha = 1.f / (1.f + __expf(-bstr[0]));
    const float bsc = 10.f * alpha * LOG2E;
    const float* base = gbias + (size_t)(b * 1024 + kt * 32 + ln) * 1024 + qt * 16 + g * 4;
    float4 va = *(const float4*)(base);              // ni=0 row
    float4 vb = *(const float4*)(base + 16 * 1024);  // ni=1 row
    float sv[8] = {va.x, va.y, va.z, va.w, vb.x, vb.y, vb.z, vb.w};
    f16x8 o;
#pragma unroll
    for (int i = 0; i < 8; ++i)
      o[i] = (_Float16)((1.f / (1.f + __expf(-sv[i])) - 0.5f) * bsc);
    *(f16x8*)(ebT + (size_t)gid * 8) = o;
    return;
  }

  // ---- GEMM: M=8192, N=1536, K=512, 128x128 tile, 8 waves (64x32 each) ----
  char* lA = smem;
  char* lB = smem + 16384;
  const int lane = t & 63;
  const int wid = t >> 6;              // 0..7
  const int wm = wid >> 2, wn = wid & 3;
  const int g = lane >> 4, ln = lane & 15;
  const int wg = (blockIdx.x & 7) * 96 + (blockIdx.x >> 3);  // 768/8 = 96
  const int m0 = (wg / 12) * 128;
  const int n0 = (wg % 12) * 128;

  const int srow = t >> 3;             // 0..63
  const int sswz = ((t & 7) * 16) ^ ((srow & 7) << 4);   // bf16-byte swizzle (B path)
  const int eswz = ((t & 7) * 8) ^ ((srow & 7) << 3);    // element swizzle (A f32 path)
  const char* gB = (const char*)Bm + (size_t)n0 * 1024;
  const float* gX = X + (size_t)m0 * 512;

  f32x4 acc[4][2] = {};

  for (int k0 = 0; k0 < 512; k0 += 64) {
    __syncthreads();
    // B: global_load_lds (bf16). A: f32 reg-load -> cvt -> ds_write (same image).
#pragma unroll
    for (int c = 0; c < 2; ++c) {
      int row = srow + 64 * c;  // (row&7)==(srow&7)
      async_load16(gB + (size_t)row * 1024 + k0 * 2 + sswz, lB + c * 8192 + t * 16);
      const float* src = gX + (size_t)row * 512 + k0 + eswz;
      float4 a0 = *(const float4*)(src);
      float4 a1 = *(const float4*)(src + 4);
      bf16x8 o;
      o[0] = (__bf16)a0.x; o[1] = (__bf16)a0.y; o[2] = (__bf16)a0.z; o[3] = (__bf16)a0.w;
      o[4] = (__bf16)a1.x; o[5] = (__bf16)a1.y; o[6] = (__bf16)a1.z; o[7] = (__bf16)a1.w;
      *(bf16x8*)(lA + c * 8192 + t * 16) = o;
    }
    __syncthreads();
#pragma unroll
    for (int ks = 0; ks < 2; ++ks) {
      bf16x8 af[4], bf[2];
#pragma unroll
      for (int i = 0; i < 4; ++i) {
        int ar = wm * 64 + i * 16 + ln;
        af[i] = *(const bf16x8*)(lA + ar * 128 + ((ks * 64 + g * 16) ^ ((ar & 7) << 4)));
      }
#pragma unroll
      for (int j = 0; j < 2; ++j) {
        int br = wn * 32 + j * 16 + ln;
        bf[j] = *(const bf16x8*)(lB + br * 128 + ((ks * 64 + g * 16) ^ ((br & 7) << 4)));
      }
#pragma unroll
      for (int i = 0; i < 4; ++i)
#pragma unroll
        for (int j = 0; j < 2; ++j)
          acc[i][j] = __builtin_amdgcn_mfma_f32_16x16x32_bf16(af[i], bf[j], acc[i][j], 0, 0, 0);
    }
  }

  // epilogue: direct stores (R18/R20-validated)
#pragma unroll
  for (int j = 0; j < 2; ++j) {
    int col = n0 + wn * 32 + j * 16 + ln;
    float bv = bias[col];
    if (col < 1024) {
      float scale = (col < 512) ? (0.125f * LOG2E) : 1.0f;
#pragma unroll
      for (int i = 0; i < 4; ++i) {
        int row0 = m0 + wm * 64 + i * 16 + g * 4;
#pragma unroll
        for (int r = 0; r < 4; ++r)
          qkO[(size_t)(row0 + r) * 1024 + col] = (__bf16)((acc[i][j][r] + bv) * scale);
      }
    } else {
      int h = (col - 1024) >> 6;
      int d = (col - 1024) & 63;
#pragma unroll
      for (int i = 0; i < 4; ++i) {
        int row0 = m0 + wm * 64 + i * 16 + g * 4;
        int b = row0 >> 10;
        bf16x4 pk;
#pragma unroll
        for (int r = 0; r < 4; ++r) pk[r] = (__bf16)(acc[i][j][r] + bv);
        *(bf16x4*)(vT + (((size_t)b * 8 + h) * 64 + d) * 1024 + (row0 & 1023)) = pk;
      }
    }
  }
}

// ---------------- gemm2: out = attn @ w2^T + b_out (fp32), 8 waves --------
__global__ __launch_bounds__(512, 4) void gemm_bt0(
    const __bf16* __restrict__ A, const __bf16* __restrict__ Bm,
    const float* __restrict__ bias, float* __restrict__ C0,
    int M, int N, int K, int nt) {
  __shared__ __align__(16) char smem[32768];
  char* lA = smem;
  char* lB = smem + 16384;
  const int t = threadIdx.x;
  const int lane = t & 63;
  const int wid = t >> 6;
  const int wm = wid >> 2, wn = wid & 3;
  const int g = lane >> 4, ln = lane & 15;
  const int qchunk = gridDim.x >> 3;
  const int wg = (blockIdx.x & 7) * qchunk + (blockIdx.x >> 3);
  const int m0 = (wg / nt) * 128;
  const int n0 = (wg % nt) * 128;

  const int srow = t >> 3;
  const int sswz = ((t & 7) * 16) ^ ((srow & 7) << 4);
  const size_t KB = (size_t)K * 2;
  const char* gA = (const char*)A + (size_t)m0 * KB;
  const char* gB = (const char*)Bm + (size_t)n0 * KB;

  f32x4 acc[4][2] = {};

  for (int k0 = 0; k0 < K; k0 += 64) {
    __syncthreads();
#pragma unroll
    for (int c = 0; c < 2; ++c) {
      int row = srow + 64 * c;
      async_load16(gA + (size_t)row * KB + k0 * 2 + sswz, lA + c * 8192 + t * 16);
      async_load16(gB + (size_t)row * KB + k0 * 2 + sswz, lB + c * 8192 + t * 16);
    }
    __syncthreads();
#pragma unroll
    for (int ks = 0; ks < 2; ++ks) {
      bf16x8 af[4], bf[2];
#pragma unroll
      for (int i = 0; i < 4; ++i) {
        int ar = wm * 64 + i * 16 + ln;
        af[i] = *(const bf16x8*)(lA + ar * 128 + ((ks * 64 + g * 16) ^ ((ar & 7) << 4)));
      }
#pragma unroll
      for (int j = 0; j < 2; ++j) {
        int br = wn * 32 + j * 16 + ln;
        bf[j] = *(const bf16x8*)(lB + br * 128 + ((ks * 64 + g * 16) ^ ((br & 7) << 4)));
      }
#pragma unroll
      for (int i = 0; i < 4; ++i)
#pragma unroll
        for (int j = 0; j < 2; ++j)
          acc[i][j] = __builtin_amdgcn_mfma_f32_16x16x32_bf16(af[i], bf[j], acc[i][j], 0, 0, 0);
    }
  }

#pragma unroll
  for (int j = 0; j < 2; ++j) {
    int col = n0 + wn * 32 + j * 16 + ln;
    float bv = bias[col];
#pragma unroll
    for (int i = 0; i < 4; ++i) {
      int row0 = m0 + wm * 64 + i * 16 + g * 4;
#pragma unroll
      for (int r = 0; r < 4; ++r)
        C0[(size_t)(row0 + r) * N + col] = acc[i][j][r] + bv;
    }
  }
}

// ---------------- fused flash attention: cooperative K/V, 4 tiles/period --
// (R17/R18/R20-validated, byte-identical)
__global__ __launch_bounds__(512, 4) void attn_fused(
    const __bf16* __restrict__ qk,    // [B][N][1024]: q(log2-prescaled)|k
    const __bf16* __restrict__ vT,    // [B*8][64 d][1024 k]
    const _Float16* __restrict__ ebT, // f16 bias table
    __bf16* __restrict__ attn) {      // [B][N][512]
  __shared__ __align__(16) char smem[73728];
  const int t = threadIdx.x;
  const int lane = t & 63;
  const int wid = t >> 6;               // 0..7 = q-tile within group
  const int g = lane >> 4, ln = lane & 15;
  const int wg = ((blockIdx.x & 7) << 6) + (blockIdx.x >> 3);  // XCD: b = wg>>6
  const int b = wg >> 6;
  const int rem = wg & 63;
  const int h = rem >> 3;               // head (shared by whole block)
  const int qg = rem & 7;
  const int qt = qg * 8 + wid;          // this wave's q-tile
  const int q0 = qt << 4;

  // buffer set s at smem + s*32768: [K0..K3 4K each][V0..V3 4K each]
  char* Ps = smem + 65536 + wid * 1024;  // per-wave P round-trip

  bf16x8 qf[2];
#pragma unroll
  for (int ks = 0; ks < 2; ++ks)
    qf[ks] = *(const bf16x8*)(qk + ((size_t)b * 1024 + q0 + ln) * 1024 +
                              h * 64 + ks * 32 + g * 8);

  float l_acc[4] = {0.f, 0.f, 0.f, 0.f};
  f32x4 o_acc[4] = {};

  const int krow = lane >> 3;
  const int ksrc = ((lane & 7) * 16) ^ (krow << 4);
  const int vrow = lane >> 2;
  const int vsrc = ((lane & 3) * 16) ^ ((vrow & 3) << 4);

  const char* qkb = (const char*)qk + (size_t)b * 1024 * 2048;
  const char* vTb = (const char*)vT + (size_t)(b * 8 + h) * 64 * 2048;
  const _Float16* ebp = ebT + (size_t)((b * 64 + qt) * 32) * 512 + lane * 8;

  auto stage = [&](int p, char* set) {
    if (wid < 4) {
#pragma unroll
      for (int j = 0; j < 4; ++j)
        async_load16(qkb + (size_t)((4 * p + j) * 32 + wid * 8 + krow) * 2048 +
                         1024 + h * 128 + ksrc,
                     set + j * 4096 + wid * 1024 + lane * 16);
    } else {
      int cc = wid - 4;
#pragma unroll
      for (int j = 0; j < 4; ++j)
        async_load16(vTb + (size_t)(cc * 16 + vrow) * 2048 + (size_t)(4 * p + j) * 64 + vsrc,
                     set + 16384 + j * 4096 + cc * 1024 + lane * 16);
    }
  };

  auto process = [&](const char* Kp, const char* Vp, f16x8 ebv) {
    bf16x8 kf[2][2];
#pragma unroll
    for (int ni = 0; ni < 2; ++ni) {
      int br = ni * 16 + ln;
      int sw = (br & 7) << 4;
#pragma unroll
      for (int ks = 0; ks < 2; ++ks)
        kf[ni][ks] = *(const bf16x8*)(Kp + br * 128 + ((ks * 64 + g * 16) ^ sw));
    }
    bf16x8 vf[4];
#pragma unroll
    for (int di = 0; di < 4; ++di)
      vf[di] = *(const bf16x8*)(Vp + (di * 16 + ln) * 64 + ((g * 16) ^ ((ln & 3) << 4)));

    f32x4 lbf0 = {(float)ebv[0], (float)ebv[1], (float)ebv[2], (float)ebv[3]};
    f32x4 lbf1 = {(float)ebv[4], (float)ebv[5], (float)ebv[6], (float)ebv[7]};
    f32x4 s[2];
    s[0] = __builtin_amdgcn_mfma_f32_16x16x32_bf16(qf[0], kf[0][0], lbf0, 0, 0, 0);
    s[0] = __builtin_amdgcn_mfma_f32_16x16x32_bf16(qf[1], kf[0][1], s[0], 0, 0, 0);
    s[1] = __builtin_amdgcn_mfma_f32_16x16x32_bf16(qf[0], kf[1][0], lbf1, 0, 0, 0);
    s[1] = __builtin_amdgcn_mfma_f32_16x16x32_bf16(qf[1], kf[1][1], s[1], 0, 0, 0);

#pragma unroll
    for (int r = 0; r < 4; ++r) {
      float p0 = fast_exp2(s[0][r]);
      float p1 = fast_exp2(s[1][r]);
      s[0][r] = p0; s[1][r] = p1;
      l_acc[r] += p0 + p1;
    }
#pragma unroll
    for (int ni = 0; ni < 2; ++ni)
#pragma unroll
      for (int r = 0; r < 4; ++r) {
        int q = g * 4 + r;
        *(__bf16*)(Ps + q * 64 + ((ni * 32 + ln * 2) ^ (((q >> 1) & 3) << 4))) =
            (__bf16)s[ni][r];
      }
    bf16x8 pf = *(const bf16x8*)(Ps + ln * 64 + ((g * 16) ^ (((ln >> 1) & 3) << 4)));

#pragma unroll
    for (int di = 0; di < 4; ++di)
      o_acc[di] = __builtin_amdgcn_mfma_f32_16x16x32_bf16(pf, vf[di], o_acc[di], 0, 0, 0);
  };

  stage(0, smem);
  f16x8 eb0 = *(const f16x8*)(ebp);
  f16x8 eb1 = *(const f16x8*)(ebp + 512);
  f16x8 eb2 = *(const f16x8*)(ebp + 1024);
  f16x8 eb3 = *(const f16x8*)(ebp + 1536);
  asm volatile("s_waitcnt vmcnt(0)" ::: "memory");
  __syncthreads();

  for (int p = 0; p < 8; ++p) {
    char* cur = smem + (p & 1) * 32768;
    char* nxt = smem + ((p + 1) & 1) * 32768;
    const int pn = (p + 1) & 7;

    stage(pn, nxt);
    f16x8 ebn0 = *(const f16x8*)(ebp + (size_t)(4 * pn) * 512);
    f16x8 ebn1 = *(const f16x8*)(ebp + (size_t)(4 * pn + 1) * 512);
    f16x8 ebn2 = *(const f16x8*)(ebp + (size_t)(4 * pn + 2) * 512);
    f16x8 ebn3 = *(const f16x8*)(ebp + (size_t)(4 * pn + 3) * 512);
    __builtin_amdgcn_sched_barrier(0);

    process(cur,         cur + 16384, eb0);
    process(cur + 4096,  cur + 20480, eb1);
    process(cur + 8192,  cur + 24576, eb2);
    process(cur + 12288, cur + 28672, eb3);

    asm volatile("s_waitcnt vmcnt(0)" ::: "memory");
    __builtin_amdgcn_sched_barrier(0);
    __syncthreads();
    eb0 = ebn0; eb1 = ebn1; eb2 = ebn2; eb3 = ebn3;
  }

#pragma unroll
  for (int r = 0; r < 4; ++r) {
    float rs = l_acc[r];
#pragma unroll
    for (int off = 1; off < 16; off <<= 1)
      rs += __shfl_xor(rs, off, 64);
    float inv = 1.f / rs;
    int q = q0 + g * 4 + r;
#pragma unroll
    for (int di = 0; di < 4; ++di)
      attn[((size_t)b * 1024 + q) * 512 + h * 64 + di * 16 + ln] =
          (__bf16)(o_acc[di][r] * inv);
  }
}

extern "C" void kernel_launch(void* const* d_in, const int* in_sizes, int n_in,
                              void* d_out, int out_size, void* d_ws, size_t ws_size,
                              hipStream_t stream) {
  const float* x     = (const float*)d_in[0];
  const float* gb    = (const float*)d_in[1];
  const float* w_in  = (const float*)d_in[2];
  const float* b_in  = (const float*)d_in[3];
  const float* w_out = (const float*)d_in[4];
  const float* b_out = (const float*)d_in[5];
  const float* bstr  = (const float*)d_in[6];

  char* ws = (char*)d_ws;
  __bf16* qk    = (__bf16*)(ws);                      // 16,777,216 B
  __bf16* vT    = (__bf16*)(ws + 16777216);           //  8,388,608 B
  __bf16* attn_buf = (__bf16*)(ws + 25165824);        //  8,388,608 B
  __bf16* w1    = (__bf16*)(ws + 33554432);           //  1,572,864 B
  __bf16* w2    = (__bf16*)(ws + 35127296);           //    524,288 B
  _Float16* ebT = (_Float16*)(ws + 35651584);         // 16,777,216 B

  // only w1/w2 need conversion now (x is consumed as f32 by gemm1 staging)
  cvtW<<<1024, 256, 0, stream>>>(w_in, w1, (1536 * 512) / 4,
                                 w_out, w2, (512 * 512) / 4);

  // gemm1 (768 blocks, f32-A staging) + ebias table (2048 blocks) fused
  gemm1_ebias<<<768 + 2048, 512, 0, stream>>>(x, w1, b_in, qk, vT, gb, bstr, ebT);
  attn_fused<<<512, 512, 0, stream>>>(qk, vT, ebT, attn_buf);
  gemm_bt0<<<256, 512, 0, stream>>>(attn_buf, w2, b_out, (float*)d_out, 8192, 512, 512, 4);
}

// Round 22
// 81.424 us; speedup vs baseline: 1.1569x; 1.0046x over previous
//
#include <hip/hip_runtime.h>

typedef __attribute__((ext_vector_type(8))) __bf16 bf16x8;
typedef __attribute__((ext_vector_type(4))) __bf16 bf16x4;
typedef __attribute__((ext_vector_type(4))) float f32x4;
typedef __attribute__((ext_vector_type(8))) _Float16 f16x8;

#define LOG2E 1.44269504088896340736f

__device__ __forceinline__ void async_load16(const void* g, void* l) {
  __builtin_amdgcn_global_load_lds(
      (const __attribute__((address_space(1))) void*)g,
      (__attribute__((address_space(3))) void*)l, 16, 0, 0);
}

__device__ __forceinline__ float fast_exp2(float x) {
#if __has_builtin(__builtin_amdgcn_exp2f)
  return __builtin_amdgcn_exp2f(x);
#else
  return __expf(x * 0.6931471805599453f);
#endif
}

// ---------------- fp32 -> bf16 convert: w1 + w2 only ----------------
__global__ void cvtW(const float* __restrict__ b, __bf16* __restrict__ ob, int nb4,
                     const float* __restrict__ c, __bf16* __restrict__ oc, int nc4) {
  int i = blockIdx.x * blockDim.x + threadIdx.x;
  int n = nb4 + nc4;
  int stride = gridDim.x * blockDim.x;
  for (; i < n; i += stride) {
    const float4* s;
    bf16x4* d;
    int j;
    if (i < nb4) { s = (const float4*)b; d = (bf16x4*)ob; j = i; }
    else { s = (const float4*)c; d = (bf16x4*)oc; j = i - nb4; }
    float4 v = s[j];
    bf16x4 o;
    o[0] = (__bf16)v.x; o[1] = (__bf16)v.y; o[2] = (__bf16)v.z; o[3] = (__bf16)v.w;
    d[j] = o;
  }
}

// ---------------- gemm1 (blocks 0..383, 256x128 tile) + ebias (384..2431) --
// 8 waves, each owns a 64x64 sub-tile (acc[4][4]): 32 MFMA per wave-K-step,
// 2x the density of the 64x32 layout -- same barriers/staging amortized.
// A staged from f32 x via reg-cvt (R21-validated); B via global_load_lds.
__global__ __launch_bounds__(512, 2) void gemm1_ebias(
    const float* __restrict__ X,    // x [8192][512] f32
    const __bf16* __restrict__ Bm,  // w1 [1536][512]
    const float* __restrict__ bias, // b_in [1536]
    __bf16* __restrict__ qkO,       // [8192][1024]
    __bf16* __restrict__ vT,        // [64][64][1024]
    const float* __restrict__ gbias, const float* __restrict__ bstr,
    _Float16* __restrict__ ebT) {
  __shared__ __align__(16) char smem[49152];
  const int t = threadIdx.x;

  if (blockIdx.x >= 384) {
    // ---- ebias table: ebT[(((b*64+qt)*32+kt)*64+lane)*8 + ni*4+r] ----
    const int gid = (blockIdx.x - 384) * 512 + t;  // 2048 x 512 = 1M
    const int lane = gid & 63;
    const int kt = (gid >> 6) & 31;
    const int qt = (gid >> 11) & 63;
    const int b = gid >> 17;
    const int g = lane >> 4, ln = lane & 15;
    const float alpha = 1.f / (1.f + __expf(-bstr[0]));
    const float bsc = 10.f * alpha * LOG2E;
    const float* base = gbias + (size_t)(b * 1024 + kt * 32 + ln) * 1024 + qt * 16 + g * 4;
    float4 va = *(const float4*)(base);              // ni=0 row
    float4 vb = *(const float4*)(base + 16 * 1024);  // ni=1 row
    float sv[8] = {va.x, va.y, va.z, va.w, vb.x, vb.y, vb.z, vb.w};
    f16x8 o;
#pragma unroll
    for (int i = 0; i < 8; ++i)
      o[i] = (_Float16)((1.f / (1.f + __expf(-sv[i])) - 0.5f) * bsc);
    *(f16x8*)(ebT + (size_t)gid * 8) = o;
    return;
  }

  // ---- GEMM: M=8192, N=1536, K=512, 256x128 tile, 8 waves (64x64 each) ----
  char* lA = smem;            // [256 rows][128B]
  char* lB = smem + 32768;    // [128 rows][128B]
  const int lane = t & 63;
  const int wid = t >> 6;              // 0..7
  const int wm = wid >> 1, wn = wid & 1;
  const int g = lane >> 4, ln = lane & 15;
  const int wg = (blockIdx.x & 7) * 48 + (blockIdx.x >> 3);  // 384/8 = 48
  const int m0 = (wg / 12) * 256;
  const int n0 = (wg % 12) * 128;

  const int srow = t >> 3;             // 0..63
  const int sswz = ((t & 7) * 16) ^ ((srow & 7) << 4);   // bf16-byte swizzle (B)
  const int eswz = ((t & 7) * 8) ^ ((srow & 7) << 3);    // f32-element swizzle (A)
  const char* gB = (const char*)Bm + (size_t)n0 * 1024;
  const float* gX = X + (size_t)m0 * 512;

  f32x4 acc[4][4] = {};

  for (int k0 = 0; k0 < 512; k0 += 64) {
    __syncthreads();
    // B: 2 chunks via global_load_lds. A: 4 chunks f32 reg-load -> cvt -> ds_write.
#pragma unroll
    for (int c = 0; c < 2; ++c) {
      int row = srow + 64 * c;
      async_load16(gB + (size_t)row * 1024 + k0 * 2 + sswz, lB + c * 8192 + t * 16);
    }
#pragma unroll
    for (int c = 0; c < 4; ++c) {
      int row = srow + 64 * c;  // (row&7)==(srow&7)
      const float* src = gX + (size_t)row * 512 + k0 + eswz;
      float4 a0 = *(const float4*)(src);
      float4 a1 = *(const float4*)(src + 4);
      bf16x8 o;
      o[0] = (__bf16)a0.x; o[1] = (__bf16)a0.y; o[2] = (__bf16)a0.z; o[3] = (__bf16)a0.w;
      o[4] = (__bf16)a1.x; o[5] = (__bf16)a1.y; o[6] = (__bf16)a1.z; o[7] = (__bf16)a1.w;
      *(bf16x8*)(lA + c * 8192 + t * 16) = o;
    }
    __syncthreads();
#pragma unroll
    for (int ks = 0; ks < 2; ++ks) {
      bf16x8 af[4], bf[4];
#pragma unroll
      for (int i = 0; i < 4; ++i) {
        int ar = wm * 64 + i * 16 + ln;
        af[i] = *(const bf16x8*)(lA + ar * 128 + ((ks * 64 + g * 16) ^ ((ar & 7) << 4)));
      }
#pragma unroll
      for (int j = 0; j < 4; ++j) {
        int br = wn * 64 + j * 16 + ln;
        bf[j] = *(const bf16x8*)(lB + br * 128 + ((ks * 64 + g * 16) ^ ((br & 7) << 4)));
      }
#pragma unroll
      for (int i = 0; i < 4; ++i)
#pragma unroll
        for (int j = 0; j < 4; ++j)
          acc[i][j] = __builtin_amdgcn_mfma_f32_16x16x32_bf16(af[i], bf[j], acc[i][j], 0, 0, 0);
    }
  }

  // epilogue: direct stores (R18/R20-validated pattern)
#pragma unroll
  for (int j = 0; j < 4; ++j) {
    int col = n0 + wn * 64 + j * 16 + ln;
    float bv = bias[col];
    if (col < 1024) {
      float scale = (col < 512) ? (0.125f * LOG2E) : 1.0f;
#pragma unroll
      for (int i = 0; i < 4; ++i) {
        int row0 = m0 + wm * 64 + i * 16 + g * 4;
#pragma unroll
        for (int r = 0; r < 4; ++r)
          qkO[(size_t)(row0 + r) * 1024 + col] = (__bf16)((acc[i][j][r] + bv) * scale);
      }
    } else {
      int h = (col - 1024) >> 6;
      int d = (col - 1024) & 63;
#pragma unroll
      for (int i = 0; i < 4; ++i) {
        int row0 = m0 + wm * 64 + i * 16 + g * 4;
        int b = row0 >> 10;
        bf16x4 pk;
#pragma unroll
        for (int r = 0; r < 4; ++r) pk[r] = (__bf16)(acc[i][j][r] + bv);
        *(bf16x4*)(vT + (((size_t)b * 8 + h) * 64 + d) * 1024 + (row0 & 1023)) = pk;
      }
    }
  }
}

// ---------------- gemm2: out = attn @ w2^T + b_out (fp32), 8 waves --------
__global__ __launch_bounds__(512, 4) void gemm_bt0(
    const __bf16* __restrict__ A, const __bf16* __restrict__ Bm,
    const float* __restrict__ bias, float* __restrict__ C0,
    int M, int N, int K, int nt) {
  __shared__ __align__(16) char smem[32768];
  char* lA = smem;
  char* lB = smem + 16384;
  const int t = threadIdx.x;
  const int lane = t & 63;
  const int wid = t >> 6;
  const int wm = wid >> 2, wn = wid & 3;
  const int g = lane >> 4, ln = lane & 15;
  const int qchunk = gridDim.x >> 3;
  const int wg = (blockIdx.x & 7) * qchunk + (blockIdx.x >> 3);
  const int m0 = (wg / nt) * 128;
  const int n0 = (wg % nt) * 128;

  const int srow = t >> 3;
  const int sswz = ((t & 7) * 16) ^ ((srow & 7) << 4);
  const size_t KB = (size_t)K * 2;
  const char* gA = (const char*)A + (size_t)m0 * KB;
  const char* gB = (const char*)Bm + (size_t)n0 * KB;

  f32x4 acc[4][2] = {};

  for (int k0 = 0; k0 < K; k0 += 64) {
    __syncthreads();
#pragma unroll
    for (int c = 0; c < 2; ++c) {
      int row = srow + 64 * c;
      async_load16(gA + (size_t)row * KB + k0 * 2 + sswz, lA + c * 8192 + t * 16);
      async_load16(gB + (size_t)row * KB + k0 * 2 + sswz, lB + c * 8192 + t * 16);
    }
    __syncthreads();
#pragma unroll
    for (int ks = 0; ks < 2; ++ks) {
      bf16x8 af[4], bf[2];
#pragma unroll
      for (int i = 0; i < 4; ++i) {
        int ar = wm * 64 + i * 16 + ln;
        af[i] = *(const bf16x8*)(lA + ar * 128 + ((ks * 64 + g * 16) ^ ((ar & 7) << 4)));
      }
#pragma unroll
      for (int j = 0; j < 2; ++j) {
        int br = wn * 32 + j * 16 + ln;
        bf[j] = *(const bf16x8*)(lB + br * 128 + ((ks * 64 + g * 16) ^ ((br & 7) << 4)));
      }
#pragma unroll
      for (int i = 0; i < 4; ++i)
#pragma unroll
        for (int j = 0; j < 2; ++j)
          acc[i][j] = __builtin_amdgcn_mfma_f32_16x16x32_bf16(af[i], bf[j], acc[i][j], 0, 0, 0);
    }
  }

#pragma unroll
  for (int j = 0; j < 2; ++j) {
    int col = n0 + wn * 32 + j * 16 + ln;
    float bv = bias[col];
#pragma unroll
    for (int i = 0; i < 4; ++i) {
      int row0 = m0 + wm * 64 + i * 16 + g * 4;
#pragma unroll
      for (int r = 0; r < 4; ++r)
        C0[(size_t)(row0 + r) * N + col] = acc[i][j][r] + bv;
    }
  }
}

// ---------------- fused flash attention: cooperative K/V, 4 tiles/period --
// (R17/R18/R20/R21-validated, byte-identical)
__global__ __launch_bounds__(512, 4) void attn_fused(
    const __bf16* __restrict__ qk,    // [B][N][1024]: q(log2-prescaled)|k
    const __bf16* __restrict__ vT,    // [B*8][64 d][1024 k]
    const _Float16* __restrict__ ebT, // f16 bias table
    __bf16* __restrict__ attn) {      // [B][N][512]
  __shared__ __align__(16) char smem[73728];
  const int t = threadIdx.x;
  const int lane = t & 63;
  const int wid = t >> 6;               // 0..7 = q-tile within group
  const int g = lane >> 4, ln = lane & 15;
  const int wg = ((blockIdx.x & 7) << 6) + (blockIdx.x >> 3);  // XCD: b = wg>>6
  const int b = wg >> 6;
  const int rem = wg & 63;
  const int h = rem >> 3;               // head (shared by whole block)
  const int qg = rem & 7;
  const int qt = qg * 8 + wid;          // this wave's q-tile
  const int q0 = qt << 4;

  // buffer set s at smem + s*32768: [K0..K3 4K each][V0..V3 4K each]
  char* Ps = smem + 65536 + wid * 1024;  // per-wave P round-trip

  bf16x8 qf[2];
#pragma unroll
  for (int ks = 0; ks < 2; ++ks)
    qf[ks] = *(const bf16x8*)(qk + ((size_t)b * 1024 + q0 + ln) * 1024 +
                              h * 64 + ks * 32 + g * 8);

  float l_acc[4] = {0.f, 0.f, 0.f, 0.f};
  f32x4 o_acc[4] = {};

  const int krow = lane >> 3;
  const int ksrc = ((lane & 7) * 16) ^ (krow << 4);
  const int vrow = lane >> 2;
  const int vsrc = ((lane & 3) * 16) ^ ((vrow & 3) << 4);

  const char* qkb = (const char*)qk + (size_t)b * 1024 * 2048;
  const char* vTb = (const char*)vT + (size_t)(b * 8 + h) * 64 * 2048;
  const _Float16* ebp = ebT + (size_t)((b * 64 + qt) * 32) * 512 + lane * 8;

  auto stage = [&](int p, char* set) {
    if (wid < 4) {
#pragma unroll
      for (int j = 0; j < 4; ++j)
        async_load16(qkb + (size_t)((4 * p + j) * 32 + wid * 8 + krow) * 2048 +
                         1024 + h * 128 + ksrc,
                     set + j * 4096 + wid * 1024 + lane * 16);
    } else {
      int cc = wid - 4;
#pragma unroll
      for (int j = 0; j < 4; ++j)
        async_load16(vTb + (size_t)(cc * 16 + vrow) * 2048 + (size_t)(4 * p + j) * 64 + vsrc,
                     set + 16384 + j * 4096 + cc * 1024 + lane * 16);
    }
  };

  auto process = [&](const char* Kp, const char* Vp, f16x8 ebv) {
    bf16x8 kf[2][2];
#pragma unroll
    for (int ni = 0; ni < 2; ++ni) {
      int br = ni * 16 + ln;
      int sw = (br & 7) << 4;
#pragma unroll
      for (int ks = 0; ks < 2; ++ks)
        kf[ni][ks] = *(const bf16x8*)(Kp + br * 128 + ((ks * 64 + g * 16) ^ sw));
    }
    bf16x8 vf[4];
#pragma unroll
    for (int di = 0; di < 4; ++di)
      vf[di] = *(const bf16x8*)(Vp + (di * 16 + ln) * 64 + ((g * 16) ^ ((ln & 3) << 4)));

    f32x4 lbf0 = {(float)ebv[0], (float)ebv[1], (float)ebv[2], (float)ebv[3]};
    f32x4 lbf1 = {(float)ebv[4], (float)ebv[5], (float)ebv[6], (float)ebv[7]};
    f32x4 s[2];
    s[0] = __builtin_amdgcn_mfma_f32_16x16x32_bf16(qf[0], kf[0][0], lbf0, 0, 0, 0);
    s[0] = __builtin_amdgcn_mfma_f32_16x16x32_bf16(qf[1], kf[0][1], s[0], 0, 0, 0);
    s[1] = __builtin_amdgcn_mfma_f32_16x16x32_bf16(qf[0], kf[1][0], lbf1, 0, 0, 0);
    s[1] = __builtin_amdgcn_mfma_f32_16x16x32_bf16(qf[1], kf[1][1], s[1], 0, 0, 0);

#pragma unroll
    for (int r = 0; r < 4; ++r) {
      float p0 = fast_exp2(s[0][r]);
      float p1 = fast_exp2(s[1][r]);
      s[0][r] = p0; s[1][r] = p1;
      l_acc[r] += p0 + p1;
    }
#pragma unroll
    for (int ni = 0; ni < 2; ++ni)
#pragma unroll
      for (int r = 0; r < 4; ++r) {
        int q = g * 4 + r;
        *(__bf16*)(Ps + q * 64 + ((ni * 32 + ln * 2) ^ (((q >> 1) & 3) << 4))) =
            (__bf16)s[ni][r];
      }
    bf16x8 pf = *(const bf16x8*)(Ps + ln * 64 + ((g * 16) ^ (((ln >> 1) & 3) << 4)));

#pragma unroll
    for (int di = 0; di < 4; ++di)
      o_acc[di] = __builtin_amdgcn_mfma_f32_16x16x32_bf16(pf, vf[di], o_acc[di], 0, 0, 0);
  };

  stage(0, smem);
  f16x8 eb0 = *(const f16x8*)(ebp);
  f16x8 eb1 = *(const f16x8*)(ebp + 512);
  f16x8 eb2 = *(const f16x8*)(ebp + 1024);
  f16x8 eb3 = *(const f16x8*)(ebp + 1536);
  asm volatile("s_waitcnt vmcnt(0)" ::: "memory");
  __syncthreads();

  for (int p = 0; p < 8; ++p) {
    char* cur = smem + (p & 1) * 32768;
    char* nxt = smem + ((p + 1) & 1) * 32768;
    const int pn = (p + 1) & 7;

    stage(pn, nxt);
    f16x8 ebn0 = *(const f16x8*)(ebp + (size_t)(4 * pn) * 512);
    f16x8 ebn1 = *(const f16x8*)(ebp + (size_t)(4 * pn + 1) * 512);
    f16x8 ebn2 = *(const f16x8*)(ebp + (size_t)(4 * pn + 2) * 512);
    f16x8 ebn3 = *(const f16x8*)(ebp + (size_t)(4 * pn + 3) * 512);
    __builtin_amdgcn_sched_barrier(0);

    process(cur,         cur + 16384, eb0);
    process(cur + 4096,  cur + 20480, eb1);
    process(cur + 8192,  cur + 24576, eb2);
    process(cur + 12288, cur + 28672, eb3);

    asm volatile("s_waitcnt vmcnt(0)" ::: "memory");
    __builtin_amdgcn_sched_barrier(0);
    __syncthreads();
    eb0 = ebn0; eb1 = ebn1; eb2 = ebn2; eb3 = ebn3;
  }

#pragma unroll
  for (int r = 0; r < 4; ++r) {
    float rs = l_acc[r];
#pragma unroll
    for (int off = 1; off < 16; off <<= 1)
      rs += __shfl_xor(rs, off, 64);
    float inv = 1.f / rs;
    int q = q0 + g * 4 + r;
#pragma unroll
    for (int di = 0; di < 4; ++di)
      attn[((size_t)b * 1024 + q) * 512 + h * 64 + di * 16 + ln] =
          (__bf16)(o_acc[di][r] * inv);
  }
}

extern "C" void kernel_launch(void* const* d_in, const int* in_sizes, int n_in,
                              void* d_out, int out_size, void* d_ws, size_t ws_size,
                              hipStream_t stream) {
  const float* x     = (const float*)d_in[0];
  const float* gb    = (const float*)d_in[1];
  const float* w_in  = (const float*)d_in[2];
  const float* b_in  = (const float*)d_in[3];
  const float* w_out = (const float*)d_in[4];
  const float* b_out = (const float*)d_in[5];
  const float* bstr  = (const float*)d_in[6];

  char* ws = (char*)d_ws;
  __bf16* qk    = (__bf16*)(ws);                      // 16,777,216 B
  __bf16* vT    = (__bf16*)(ws + 16777216);           //  8,388,608 B
  __bf16* attn_buf = (__bf16*)(ws + 25165824);        //  8,388,608 B
  __bf16* w1    = (__bf16*)(ws + 33554432);           //  1,572,864 B
  __bf16* w2    = (__bf16*)(ws + 35127296);           //    524,288 B
  _Float16* ebT = (_Float16*)(ws + 35651584);         // 16,777,216 B

  cvtW<<<1024, 256, 0, stream>>>(w_in, w1, (1536 * 512) / 4,
                                 w_out, w2, (512 * 512) / 4);

  // gemm1 (384 blocks, 256x128 tile, f32-A staging) + ebias (2048 blocks)
  gemm1_ebias<<<384 + 2048, 512, 0, stream>>>(x, w1, b_in, qk, vT, gb, bstr, ebT);
  attn_fused<<<512, 512, 0, stream>>>(qk, vT, ebT, attn_buf);
  gemm_bt0<<<256, 512, 0, stream>>>(attn_buf, w2, b_out, (float*)d_out, 8192, 512, 512, 4);
}